// Round 4
// baseline (202.661 us; speedup 1.0000x reference)
//
#include <hip/hip_runtime.h>
#include <hip/hip_bf16.h>
#include <math.h>

#define B_   4
#define T_   2048
#define KDIM 1024
#define H_   16
#define D_   64
#define BH_  (B_*H_)      // 64
#define M_   (B_*T_)      // 8192
#define NKT  (KDIM/64)    // 16 K-tiles

typedef __bf16 bf16;
typedef __bf16 bf16x8 __attribute__((ext_vector_type(8)));
typedef __bf16 bf16x4 __attribute__((ext_vector_type(4)));
typedef float  f32x4  __attribute__((ext_vector_type(4)));
typedef float  f32x16 __attribute__((ext_vector_type(16)));
typedef unsigned int u32;
typedef u32 u32x4 __attribute__((ext_vector_type(4)));

static __device__ __forceinline__ f32x4 mfma16(bf16x8 a, bf16x8 b, f32x4 c) {
    return __builtin_amdgcn_mfma_f32_16x16x32_bf16(a, b, c, 0, 0, 0);
}
static __device__ __forceinline__ f32x16 mfma32(bf16x8 a, bf16x8 b, f32x16 c) {
    return __builtin_amdgcn_mfma_f32_32x32x16_bf16(a, b, c, 0, 0, 0);
}
static __device__ __forceinline__ float exp2_fast(float x) {
    float r; asm("v_exp_f32 %0, %1" : "=v"(r) : "v"(x)); return r;
}

// ---------------- fp32 -> bf16 conversion (vectorized) ----------------
__global__ void cvt_f32_to_bf16(const float* __restrict__ src, bf16* __restrict__ dst, int n4) {
    int i = blockIdx.x * blockDim.x + threadIdx.x;
    if (i >= n4) return;
    float4 v = reinterpret_cast<const float4*>(src)[i];
    bf16x4 o;
    o.x = (bf16)v.x; o.y = (bf16)v.y; o.z = (bf16)v.z; o.w = (bf16)v.w;
    reinterpret_cast<bf16x4*>(dst)[i] = o;
}

// ---------------- fused QKV GEMM: C[8192][3072] = x · Wflat^T ----------------
// 256x128 tile, BK=64, 8 waves (4M x 2N), counted-vmcnt double-buffer pipeline,
// st_16x32 LDS swizzle (pre-swizzled global source for global_load_lds),
// setprio around MFMA clusters, bijective XCD block swizzle.
__global__ __launch_bounds__(512) void proj_gemm256(
    const bf16* __restrict__ xb, const bf16* __restrict__ Wflat,
    bf16* __restrict__ Qb, bf16* __restrict__ Kb, bf16* __restrict__ Vtb)
{
    __shared__ __align__(16) char As[2][256*64*2];  // 32 KB per buffer
    __shared__ __align__(16) char Bs[2][128*64*2];  // 16 KB per buffer

    const int tid  = threadIdx.x;
    const int wid  = tid >> 6;
    const int lane = tid & 63;
    const int l15  = lane & 15, l4 = lane >> 4;
    const int wavem = wid >> 1, waven = wid & 1;

    // XCD-aware bijective swizzle: 768 = 8 XCDs x 96; B-panel stationary per XCD
    const int orig = blockIdx.x;
    const int wg   = (orig & 7) * 96 + (orig >> 3);
    const int mblk = wg & 31, nblk = wg >> 5;          // 32 x 24
    const int row0 = mblk * 256, col0 = nblk * 128;

    // ---- staging source pointers (pre-swizzled: LDS[x] = Gtile[swz(x)]) ----
    // A: 2048 16B-chunks; thread handles q*512+tid, q=0..3.  B: q=0..1.
    const bf16* asrc[4];
#pragma unroll
    for (int q = 0; q < 4; ++q) {
        int c   = q*512 + tid;
        int rr  = c >> 3;                  // 0..255
        int cb  = (c & 7) * 16;            // byte col 0..112
        int cbs = cb ^ ((rr & 4) << 3);    // st_16x32 inverse-swizzle (involution)
        asrc[q] = xb + (size_t)(row0 + rr)*KDIM + (cbs >> 1);
    }
    const bf16* bsrc[2];
#pragma unroll
    for (int q = 0; q < 2; ++q) {
        int c   = q*512 + tid;
        int rr  = c >> 3;                  // 0..127
        int cb  = (c & 7) * 16;
        int cbs = cb ^ ((rr & 4) << 3);
        bsrc[q] = Wflat + (size_t)(col0 + rr)*KDIM + (cbs >> 1);
    }

    auto stage = [&](int kt, int b) {
        const int k0 = kt * 64;
#pragma unroll
        for (int q = 0; q < 4; ++q) {
            char* la = As[b] + (q*512 + wid*64)*16;   // wave-uniform base
            __builtin_amdgcn_global_load_lds(
                (const __attribute__((address_space(1))) void*)(asrc[q] + k0),
                (__attribute__((address_space(3))) void*)la, 16, 0, 0);
        }
#pragma unroll
        for (int q = 0; q < 2; ++q) {
            char* lb = Bs[b] + (q*512 + wid*64)*16;
            __builtin_amdgcn_global_load_lds(
                (const __attribute__((address_space(1))) void*)(bsrc[q] + k0),
                (__attribute__((address_space(3))) void*)lb, 16, 0, 0);
        }
    };

    f32x4 acc[4][4] = {};

    // ds_read geometry (swizzled): byte = row*128 + ((kk*64 + l4*16) ^ ((l15&4)<<3))
    const int sw    = (l15 & 4) << 3;
    const int arow  = (wavem*64 + l15) * 128;
    const int brow  = (waven*64 + l15) * 128;

    auto compute = [&](int b) {
        const char* Ap = As[b];
        const char* Bp = Bs[b];
#pragma unroll
        for (int kk = 0; kk < 2; ++kk) {
            const int cbk = (kk*64 + l4*16) ^ sw;
            bf16x8 af[4], bfr[4];
#pragma unroll
            for (int m = 0; m < 4; ++m)
                af[m] = *reinterpret_cast<const bf16x8*>(Ap + arow + m*2048 + cbk);
#pragma unroll
            for (int n = 0; n < 4; ++n)
                bfr[n] = *reinterpret_cast<const bf16x8*>(Bp + brow + n*2048 + cbk);
            __builtin_amdgcn_s_setprio(1);
#pragma unroll
            for (int m = 0; m < 4; ++m)
#pragma unroll
                for (int n = 0; n < 4; ++n)
                    acc[m][n] = mfma16(af[m], bfr[n], acc[m][n]);
            __builtin_amdgcn_s_setprio(0);
        }
    };

    // ---- pipeline: stage(0), stage(1); iter t: wait tile t, compute, stage(t+2) ----
    stage(0, 0);
    stage(1, 1);

    for (int t = 0; t < NKT - 1; ++t) {
        const int b = t & 1;
        asm volatile("s_waitcnt vmcnt(6)" ::: "memory");   // tile t landed; t+1 in flight
        __builtin_amdgcn_sched_barrier(0);
        __builtin_amdgcn_s_barrier();
        __builtin_amdgcn_sched_barrier(0);
        compute(b);
        asm volatile("s_waitcnt lgkmcnt(0)" ::: "memory"); // all reads of buf b retired
        __builtin_amdgcn_sched_barrier(0);
        __builtin_amdgcn_s_barrier();
        __builtin_amdgcn_sched_barrier(0);
        if (t < NKT - 2) stage(t + 2, b);                  // overwrite freed buffer
    }
    // last tile
    asm volatile("s_waitcnt vmcnt(0)" ::: "memory");
    __builtin_amdgcn_sched_barrier(0);
    __builtin_amdgcn_s_barrier();
    __builtin_amdgcn_sched_barrier(0);
    compute((NKT - 1) & 1);

    // ---- epilogue: C/D layout col=l15, row=l4*4+r ----
#pragma unroll
    for (int m = 0; m < 4; ++m)
#pragma unroll
        for (int n = 0; n < 4; ++n)
#pragma unroll
            for (int r = 0; r < 4; ++r) {
                int gi = row0 + wavem*64 + m*16 + l4*4 + r;   // 0..8191
                int gj = col0 + waven*64 + n*16 + l15;        // 0..3071
                int wz  = gj >> 10;
                int gjw = gj & 1023;
                float v = acc[m][n][r];
                if (wz == 0) v *= 0.18033688011112042f;       // 0.125*log2(e) into Q
                bf16 o = (bf16)v;
                int bb = gi >> 11, tt = gi & (T_-1);
                int hh = gjw >> 6, dd = gjw & (D_-1);
                size_t bh = (size_t)bb*H_ + hh;
                if (wz == 0)      Qb [(bh*T_ + tt)*D_ + dd] = o;
                else if (wz == 1) Kb [(bh*T_ + tt)*D_ + dd] = o;
                else              Vtb[(bh*D_ + dd)*T_ + tt] = o;
            }
}

// ---------------- causal flash attention v3 (unchanged from R3, proven) ----------------
__global__ __launch_bounds__(256) void flash_attn3(
    const bf16* __restrict__ Qb, const bf16* __restrict__ Kb,
    const bf16* __restrict__ Vtb, float* __restrict__ out)
{
    __shared__ __align__(16) char Ksm[8192];   // [kv=64][d=64] bf16, rows XOR-swizzled
    __shared__ __align__(16) char Vsm[8192];   // [d=64][kv=64] bf16, rows XOR-swizzled

    const int tid  = threadIdx.x;
    const int wid  = tid >> 6;
    const int lane = tid & 63;
    const int l31  = lane & 31;
    const int hi   = lane >> 5;

    const int orig = blockIdx.x;                       // 1024 blocks
    const int wg   = (orig & 7) * 128 + (orig >> 3);
    const int bh   = wg >> 4;
    const int qblk = (15 - (wg & 15)) * 128;           // heavy tiles first per bh
    const int q0   = qblk + wid * 32;
    const int q_abs = q0 + l31;

    const bf16* qp = Qb + ((size_t)bh*T_ + q_abs)*D_ + hi*8;
    bf16x8 qf[4];
#pragma unroll
    for (int j = 0; j < 4; ++j)
        qf[j] = *reinterpret_cast<const bf16x8*>(qp + j*16);

    const bf16* kbase = Kb  + (size_t)bh*T_*D_;
    const bf16* vbase = Vtb + (size_t)bh*D_*T_;

    f32x16 o0 = {}; f32x16 o1 = {};
    float lsum = 0.f;

    const int my_nt  = (q0 + 31) >> 6;
    const int blk_nt = qblk/64 + 1;
    const int tmaskb = q_abs - 4*hi;

    const int r0 = tid >> 3,          r1 = (tid + 256) >> 3;
    const int e0 = (tid & 7) * 8,     e1 = e0;
    const u32 lds0 = (u32)((r0*128 + e0*2) ^ ((r0 & 7) << 4));
    const u32 lds1 = (u32)((r1*128 + e1*2) ^ ((r1 & 7) << 4));

    u32x4 kr0, kr1, vr0, vr1;
    auto issue = [&](int nt) {
        kr0 = *reinterpret_cast<const u32x4*>(kbase + ((size_t)(nt*64 + r0))*D_ + e0);
        kr1 = *reinterpret_cast<const u32x4*>(kbase + ((size_t)(nt*64 + r1))*D_ + e1);
        vr0 = *reinterpret_cast<const u32x4*>(vbase + (size_t)r0*T_ + nt*64 + e0);
        vr1 = *reinterpret_cast<const u32x4*>(vbase + (size_t)r1*T_ + nt*64 + e1);
    };
    issue(0);

    auto subtile = [&](int s, int kvb_abs, bool maskit, bf16x8& pA, bf16x8& pB) {
        f32x16 sacc = {};
        const int row = s*32 + l31;
        const int swk = (row & 7) << 4;
#pragma unroll
        for (int j = 0; j < 4; ++j) {
            bf16x8 kf = *reinterpret_cast<const bf16x8*>(Ksm + ((row*128 + j*32 + hi*16) ^ swk));
            sacc = mfma32(kf, qf[j], sacc);
        }
        const int tlim = tmaskb - kvb_abs;
        float p[16];
#pragma unroll
        for (int r = 0; r < 16; ++r) {
            const int crow0 = (r & 3) + 8*(r >> 2);
            float sv = sacc[r];
            if (maskit) sv = (crow0 > tlim) ? -INFINITY : sv;
            p[r] = exp2_fast(sv);
        }
        {
            float a0 = p[0]+p[1],   a1 = p[2]+p[3],   a2 = p[4]+p[5],   a3 = p[6]+p[7];
            float a4 = p[8]+p[9],   a5 = p[10]+p[11], a6 = p[12]+p[13], a7 = p[14]+p[15];
            lsum += ((a0+a1) + (a2+a3)) + ((a4+a5) + (a6+a7));
        }
        u32 w[8];
#pragma unroll
        for (int i = 0; i < 8; ++i) {
            u32 wv;
            asm("v_cvt_pk_bf16_f32 %0, %1, %2" : "=v"(wv) : "v"(p[2*i]), "v"(p[2*i+1]));
            w[i] = wv;
        }
        u32 a0w = w[0], a2w = w[2];
        asm("v_permlane32_swap_b32 %0, %1" : "+v"(a0w), "+v"(a2w));
        u32 a1w = w[1], a3w = w[3];
        asm("v_permlane32_swap_b32 %0, %1" : "+v"(a1w), "+v"(a3w));
        u32 b0w = w[4], b2w = w[6];
        asm("v_permlane32_swap_b32 %0, %1" : "+v"(b0w), "+v"(b2w));
        u32 b1w = w[5], b3w = w[7];
        asm("v_permlane32_swap_b32 %0, %1" : "+v"(b1w), "+v"(b3w));
        u32x4 A0 = {a0w, a1w, a2w, a3w};
        u32x4 A1 = {b0w, b1w, b2w, b3w};
        pA = __builtin_bit_cast(bf16x8, A0);
        pB = __builtin_bit_cast(bf16x8, A1);
    };

    auto pv = [&](int ks, bf16x8 pf) {
        const int swv = (l31 & 7) << 4;
        const int colb = ks*32 + hi*16;
        bf16x8 v0 = *reinterpret_cast<const bf16x8*>(Vsm + ((l31*128 + colb) ^ swv));
        bf16x8 v1 = *reinterpret_cast<const bf16x8*>(Vsm + (((32 + l31)*128 + colb) ^ swv));
        o0 = mfma32(v0, pf, o0);
        o1 = mfma32(v1, pf, o1);
    };

    for (int nt = 0; nt <= blk_nt; ++nt) {
        __syncthreads();
        *reinterpret_cast<u32x4*>(Ksm + lds0) = kr0;
        *reinterpret_cast<u32x4*>(Ksm + lds1) = kr1;
        *reinterpret_cast<u32x4*>(Vsm + lds0) = vr0;
        *reinterpret_cast<u32x4*>(Vsm + lds1) = vr1;
        __syncthreads();
        if (nt < blk_nt) issue(nt + 1);

        if (nt <= my_nt) {
            const bool partial = (nt == my_nt);
            const int  nsub = (!partial || (q0 & 32)) ? 2 : 1;
            bf16x8 pA, pB;
            subtile(0, nt*64, partial, pA, pB);
            pv(0, pA);
            pv(1, pB);
            if (nsub == 2) {
                subtile(1, nt*64 + 32, partial, pA, pB);
                pv(2, pA);
                pv(3, pB);
            }
        }
    }

    lsum += __shfl_xor(lsum, 32);
    const float inv = 1.0f / lsum;
    const int bb = bh >> 4, hh = bh & 15;
    float* orow = out + ((size_t)bb*T_ + q_abs)*KDIM + hh*64 + hi*4;
#pragma unroll
    for (int g = 0; g < 4; ++g) {
        f32x4 v0, v1;
#pragma unroll
        for (int j = 0; j < 4; ++j) { v0[j] = o0[g*4+j]*inv; v1[j] = o1[g*4+j]*inv; }
        *reinterpret_cast<f32x4*>(orow + g*8)      = v0;
        *reinterpret_cast<f32x4*>(orow + 32 + g*8) = v1;
    }
}

extern "C" void kernel_launch(void* const* d_in, const int* in_sizes, int n_in,
                              void* d_out, int out_size, void* d_ws, size_t ws_size,
                              hipStream_t stream) {
    (void)in_sizes; (void)n_in; (void)out_size; (void)ws_size;
    const float* x  = (const float*)d_in[0];
    const float* Wq = (const float*)d_in[1];
    const float* Wk = (const float*)d_in[2];
    const float* Wv = (const float*)d_in[3];
    float* out = (float*)d_out;

    bf16* xb  = (bf16*)d_ws;
    bf16* Wb  = xb + (size_t)M_*KDIM;
    bf16* Qb  = Wb + (size_t)3*KDIM*KDIM;
    bf16* Kb  = Qb + (size_t)M_*KDIM;
    bf16* Vtb = Kb + (size_t)M_*KDIM;

    const int n4x = M_*KDIM/4;
    const int n4w = KDIM*KDIM/4;
    cvt_f32_to_bf16<<<(n4x+255)/256, 256, 0, stream>>>(x,  xb, n4x);
    cvt_f32_to_bf16<<<(n4w+255)/256, 256, 0, stream>>>(Wq, Wb,               n4w);
    cvt_f32_to_bf16<<<(n4w+255)/256, 256, 0, stream>>>(Wk, Wb + (size_t)KDIM*KDIM,   n4w);
    cvt_f32_to_bf16<<<(n4w+255)/256, 256, 0, stream>>>(Wv, Wb + (size_t)2*KDIM*KDIM, n4w);

    proj_gemm256<<<dim3(768), 512, 0, stream>>>(xb, Wb, Qb, Kb, Vtb);
    flash_attn3<<<dim3(BH_*16), 256, 0, stream>>>(Qb, Kb, Vtb, out);
}

// Round 5
// 167.691 us; speedup vs baseline: 1.2085x; 1.2085x over previous
//
#include <hip/hip_runtime.h>
#include <hip/hip_bf16.h>
#include <math.h>

#define B_   4
#define T_   2048
#define KDIM 1024
#define H_   16
#define D_   64
#define BH_  (B_*H_)      // 64
#define M_   (B_*T_)      // 8192
#define NKT  (KDIM/64)    // 16 K-tiles

typedef __bf16 bf16;
typedef __bf16 bf16x8 __attribute__((ext_vector_type(8)));
typedef __bf16 bf16x4 __attribute__((ext_vector_type(4)));
typedef float  f32x4  __attribute__((ext_vector_type(4)));
typedef float  f32x16 __attribute__((ext_vector_type(16)));
typedef unsigned int u32;
typedef u32 u32x4 __attribute__((ext_vector_type(4)));

static __device__ __forceinline__ f32x4 mfma16(bf16x8 a, bf16x8 b, f32x4 c) {
    return __builtin_amdgcn_mfma_f32_16x16x32_bf16(a, b, c, 0, 0, 0);
}
static __device__ __forceinline__ f32x16 mfma32(bf16x8 a, bf16x8 b, f32x16 c) {
    return __builtin_amdgcn_mfma_f32_32x32x16_bf16(a, b, c, 0, 0, 0);
}
static __device__ __forceinline__ float exp2_fast(float x) {
    float r; asm("v_exp_f32 %0, %1" : "=v"(r) : "v"(x)); return r;
}

// ---------------- fp32 -> bf16 conversion (vectorized) ----------------
__global__ void cvt_f32_to_bf16(const float* __restrict__ src, bf16* __restrict__ dst, int n4) {
    int i = blockIdx.x * blockDim.x + threadIdx.x;
    if (i >= n4) return;
    float4 v = reinterpret_cast<const float4*>(src)[i];
    bf16x4 o;
    o.x = (bf16)v.x; o.y = (bf16)v.y; o.z = (bf16)v.z; o.w = (bf16)v.w;
    reinterpret_cast<bf16x4*>(dst)[i] = o;
}

// ---------------- fused QKV GEMM: C[8192][3072] = x · Wflat^T ----------------
// 256x128 tile, BK=64, 8 waves (4M x 2N), counted-vmcnt double-buffer pipeline.
// L2-tiled XCD mapping: concurrent 32 blocks/XCD = 4 mblk x 8 nblk (2MB A + 2MB W in L2).
// 3-bit XOR LDS swizzle (pre-swizzled global source; conflict-free ds_read_b128).
__global__ __launch_bounds__(512) void proj_gemm256(
    const bf16* __restrict__ xb, const bf16* __restrict__ Wflat,
    bf16* __restrict__ Qb, bf16* __restrict__ Kb, bf16* __restrict__ Vtb)
{
    __shared__ __align__(16) char As[2][256*64*2];  // 32 KB per buffer
    __shared__ __align__(16) char Bs[2][128*64*2];  // 16 KB per buffer

    const int tid  = threadIdx.x;
    const int wid  = tid >> 6;
    const int lane = tid & 63;
    const int l15  = lane & 15, l4 = lane >> 4;
    const int wavem = wid >> 1, waven = wid & 1;

    // L2-tiled XCD mapping (768 = 8 XCDs x 96 blocks; 32 concurrent/XCD = 4m x 8n)
    const int orig = blockIdx.x;
    const int xcd  = orig & 7;
    const int idx  = orig >> 3;                 // 0..95
    const int mblk = xcd * 4 + (idx & 3);       // 0..31
    const int nblk = idx >> 2;                  // 0..23
    const int row0 = mblk * 256, col0 = nblk * 128;

    // ---- staging source pointers (pre-swizzled: LDS[r][cb] = G[r][cb ^ ((r&7)<<4)]) ----
    const bf16* asrc[4];
#pragma unroll
    for (int q = 0; q < 4; ++q) {
        int c   = q*512 + tid;
        int rr  = c >> 3;                       // 0..255
        int cb  = (c & 7) * 16;                 // byte col 0..112
        int cbs = cb ^ ((rr & 7) << 4);         // involution within 128B row
        asrc[q] = xb + (size_t)(row0 + rr)*KDIM + (cbs >> 1);
    }
    const bf16* bsrc[2];
#pragma unroll
    for (int q = 0; q < 2; ++q) {
        int c   = q*512 + tid;
        int rr  = c >> 3;                       // 0..127
        int cb  = (c & 7) * 16;
        int cbs = cb ^ ((rr & 7) << 4);
        bsrc[q] = Wflat + (size_t)(col0 + rr)*KDIM + (cbs >> 1);
    }

    auto stage = [&](int kt, int b) {
        const int k0 = kt * 64;
#pragma unroll
        for (int q = 0; q < 4; ++q) {
            char* la = As[b] + (q*512 + wid*64)*16;   // wave-uniform base
            __builtin_amdgcn_global_load_lds(
                (const __attribute__((address_space(1))) void*)(asrc[q] + k0),
                (__attribute__((address_space(3))) void*)la, 16, 0, 0);
        }
#pragma unroll
        for (int q = 0; q < 2; ++q) {
            char* lb = Bs[b] + (q*512 + wid*64)*16;
            __builtin_amdgcn_global_load_lds(
                (const __attribute__((address_space(1))) void*)(bsrc[q] + k0),
                (__attribute__((address_space(3))) void*)lb, 16, 0, 0);
        }
    };

    f32x4 acc[4][4] = {};

    // ds_read (swizzled): byte = row*128 + (col ^ ((row&7)<<4)); row&7 == l15&7
    const int sw    = (l15 & 7) << 4;
    const int arow  = (wavem*64 + l15) * 128;
    const int brow  = (waven*64 + l15) * 128;

    auto compute = [&](int b) {
        const char* Ap = As[b];
        const char* Bp = Bs[b];
#pragma unroll
        for (int kk = 0; kk < 2; ++kk) {
            const int cbk = (kk*64 + l4*16) ^ sw;
            bf16x8 af[4], bfr[4];
#pragma unroll
            for (int m = 0; m < 4; ++m)
                af[m] = *reinterpret_cast<const bf16x8*>(Ap + arow + m*2048 + cbk);
#pragma unroll
            for (int n = 0; n < 4; ++n)
                bfr[n] = *reinterpret_cast<const bf16x8*>(Bp + brow + n*2048 + cbk);
            __builtin_amdgcn_s_setprio(1);
#pragma unroll
            for (int m = 0; m < 4; ++m)
#pragma unroll
                for (int n = 0; n < 4; ++n)
                    acc[m][n] = mfma16(af[m], bfr[n], acc[m][n]);
            __builtin_amdgcn_s_setprio(0);
        }
    };

    // ---- pipeline: stage(0), stage(1); iter t: wait tile t, compute, stage(t+2) ----
    stage(0, 0);
    stage(1, 1);

    for (int t = 0; t < NKT - 1; ++t) {
        const int b = t & 1;
        asm volatile("s_waitcnt vmcnt(6)" ::: "memory");   // tile t landed; t+1 in flight
        __builtin_amdgcn_sched_barrier(0);
        __builtin_amdgcn_s_barrier();
        __builtin_amdgcn_sched_barrier(0);
        compute(b);
        asm volatile("s_waitcnt lgkmcnt(0)" ::: "memory"); // all reads of buf b retired
        __builtin_amdgcn_sched_barrier(0);
        __builtin_amdgcn_s_barrier();
        __builtin_amdgcn_sched_barrier(0);
        if (t < NKT - 2) stage(t + 2, b);                  // overwrite freed buffer
    }
    // last tile
    asm volatile("s_waitcnt vmcnt(0)" ::: "memory");
    __builtin_amdgcn_sched_barrier(0);
    __builtin_amdgcn_s_barrier();
    __builtin_amdgcn_sched_barrier(0);
    compute((NKT - 1) & 1);

    // ---- epilogue: C/D layout col=l15, row=l4*4+r ----
#pragma unroll
    for (int m = 0; m < 4; ++m)
#pragma unroll
        for (int n = 0; n < 4; ++n)
#pragma unroll
            for (int r = 0; r < 4; ++r) {
                int gi = row0 + wavem*64 + m*16 + l4*4 + r;   // 0..8191
                int gj = col0 + waven*64 + n*16 + l15;        // 0..3071
                int wz  = gj >> 10;
                int gjw = gj & 1023;
                float v = acc[m][n][r];
                if (wz == 0) v *= 0.18033688011112042f;       // 0.125*log2(e) into Q
                bf16 o = (bf16)v;
                int bb = gi >> 11, tt = gi & (T_-1);
                int hh = gjw >> 6, dd = gjw & (D_-1);
                size_t bh = (size_t)bb*H_ + hh;
                if (wz == 0)      Qb [(bh*T_ + tt)*D_ + dd] = o;
                else if (wz == 1) Kb [(bh*T_ + tt)*D_ + dd] = o;
                else              Vtb[(bh*D_ + dd)*T_ + tt] = o;
            }
}

// ---------------- causal flash attention v3 (unchanged from R3, proven) ----------------
__global__ __launch_bounds__(256) void flash_attn3(
    const bf16* __restrict__ Qb, const bf16* __restrict__ Kb,
    const bf16* __restrict__ Vtb, float* __restrict__ out)
{
    __shared__ __align__(16) char Ksm[8192];   // [kv=64][d=64] bf16, rows XOR-swizzled
    __shared__ __align__(16) char Vsm[8192];   // [d=64][kv=64] bf16, rows XOR-swizzled

    const int tid  = threadIdx.x;
    const int wid  = tid >> 6;
    const int lane = tid & 63;
    const int l31  = lane & 31;
    const int hi   = lane >> 5;

    const int orig = blockIdx.x;                       // 1024 blocks
    const int wg   = (orig & 7) * 128 + (orig >> 3);
    const int bh   = wg >> 4;
    const int qblk = (15 - (wg & 15)) * 128;           // heavy tiles first per bh
    const int q0   = qblk + wid * 32;
    const int q_abs = q0 + l31;

    const bf16* qp = Qb + ((size_t)bh*T_ + q_abs)*D_ + hi*8;
    bf16x8 qf[4];
#pragma unroll
    for (int j = 0; j < 4; ++j)
        qf[j] = *reinterpret_cast<const bf16x8*>(qp + j*16);

    const bf16* kbase = Kb  + (size_t)bh*T_*D_;
    const bf16* vbase = Vtb + (size_t)bh*D_*T_;

    f32x16 o0 = {}; f32x16 o1 = {};
    float lsum = 0.f;

    const int my_nt  = (q0 + 31) >> 6;
    const int blk_nt = qblk/64 + 1;
    const int tmaskb = q_abs - 4*hi;

    const int r0 = tid >> 3,          r1 = (tid + 256) >> 3;
    const int e0 = (tid & 7) * 8,     e1 = e0;
    const u32 lds0 = (u32)((r0*128 + e0*2) ^ ((r0 & 7) << 4));
    const u32 lds1 = (u32)((r1*128 + e1*2) ^ ((r1 & 7) << 4));

    u32x4 kr0, kr1, vr0, vr1;
    auto issue = [&](int nt) {
        kr0 = *reinterpret_cast<const u32x4*>(kbase + ((size_t)(nt*64 + r0))*D_ + e0);
        kr1 = *reinterpret_cast<const u32x4*>(kbase + ((size_t)(nt*64 + r1))*D_ + e1);
        vr0 = *reinterpret_cast<const u32x4*>(vbase + (size_t)r0*T_ + nt*64 + e0);
        vr1 = *reinterpret_cast<const u32x4*>(vbase + (size_t)r1*T_ + nt*64 + e1);
    };
    issue(0);

    auto subtile = [&](int s, int kvb_abs, bool maskit, bf16x8& pA, bf16x8& pB) {
        f32x16 sacc = {};
        const int row = s*32 + l31;
        const int swk = (row & 7) << 4;
#pragma unroll
        for (int j = 0; j < 4; ++j) {
            bf16x8 kf = *reinterpret_cast<const bf16x8*>(Ksm + ((row*128 + j*32 + hi*16) ^ swk));
            sacc = mfma32(kf, qf[j], sacc);
        }
        const int tlim = tmaskb - kvb_abs;
        float p[16];
#pragma unroll
        for (int r = 0; r < 16; ++r) {
            const int crow0 = (r & 3) + 8*(r >> 2);
            float sv = sacc[r];
            if (maskit) sv = (crow0 > tlim) ? -INFINITY : sv;
            p[r] = exp2_fast(sv);
        }
        {
            float a0 = p[0]+p[1],   a1 = p[2]+p[3],   a2 = p[4]+p[5],   a3 = p[6]+p[7];
            float a4 = p[8]+p[9],   a5 = p[10]+p[11], a6 = p[12]+p[13], a7 = p[14]+p[15];
            lsum += ((a0+a1) + (a2+a3)) + ((a4+a5) + (a6+a7));
        }
        u32 w[8];
#pragma unroll
        for (int i = 0; i < 8; ++i) {
            u32 wv;
            asm("v_cvt_pk_bf16_f32 %0, %1, %2" : "=v"(wv) : "v"(p[2*i]), "v"(p[2*i+1]));
            w[i] = wv;
        }
        u32 a0w = w[0], a2w = w[2];
        asm("v_permlane32_swap_b32 %0, %1" : "+v"(a0w), "+v"(a2w));
        u32 a1w = w[1], a3w = w[3];
        asm("v_permlane32_swap_b32 %0, %1" : "+v"(a1w), "+v"(a3w));
        u32 b0w = w[4], b2w = w[6];
        asm("v_permlane32_swap_b32 %0, %1" : "+v"(b0w), "+v"(b2w));
        u32 b1w = w[5], b3w = w[7];
        asm("v_permlane32_swap_b32 %0, %1" : "+v"(b1w), "+v"(b3w));
        u32x4 A0 = {a0w, a1w, a2w, a3w};
        u32x4 A1 = {b0w, b1w, b2w, b3w};
        pA = __builtin_bit_cast(bf16x8, A0);
        pB = __builtin_bit_cast(bf16x8, A1);
    };

    auto pv = [&](int ks, bf16x8 pf) {
        const int swv = (l31 & 7) << 4;
        const int colb = ks*32 + hi*16;
        bf16x8 v0 = *reinterpret_cast<const bf16x8*>(Vsm + ((l31*128 + colb) ^ swv));
        bf16x8 v1 = *reinterpret_cast<const bf16x8*>(Vsm + (((32 + l31)*128 + colb) ^ swv));
        o0 = mfma32(v0, pf, o0);
        o1 = mfma32(v1, pf, o1);
    };

    for (int nt = 0; nt <= blk_nt; ++nt) {
        __syncthreads();
        *reinterpret_cast<u32x4*>(Ksm + lds0) = kr0;
        *reinterpret_cast<u32x4*>(Ksm + lds1) = kr1;
        *reinterpret_cast<u32x4*>(Vsm + lds0) = vr0;
        *reinterpret_cast<u32x4*>(Vsm + lds1) = vr1;
        __syncthreads();
        if (nt < blk_nt) issue(nt + 1);

        if (nt <= my_nt) {
            const bool partial = (nt == my_nt);
            const int  nsub = (!partial || (q0 & 32)) ? 2 : 1;
            bf16x8 pA, pB;
            subtile(0, nt*64, partial, pA, pB);
            pv(0, pA);
            pv(1, pB);
            if (nsub == 2) {
                subtile(1, nt*64 + 32, partial, pA, pB);
                pv(2, pA);
                pv(3, pB);
            }
        }
    }

    lsum += __shfl_xor(lsum, 32);
    const float inv = 1.0f / lsum;
    const int bb = bh >> 4, hh = bh & 15;
    float* orow = out + ((size_t)bb*T_ + q_abs)*KDIM + hh*64 + hi*4;
#pragma unroll
    for (int g = 0; g < 4; ++g) {
        f32x4 v0, v1;
#pragma unroll
        for (int j = 0; j < 4; ++j) { v0[j] = o0[g*4+j]*inv; v1[j] = o1[g*4+j]*inv; }
        *reinterpret_cast<f32x4*>(orow + g*8)      = v0;
        *reinterpret_cast<f32x4*>(orow + 32 + g*8) = v1;
    }
}

extern "C" void kernel_launch(void* const* d_in, const int* in_sizes, int n_in,
                              void* d_out, int out_size, void* d_ws, size_t ws_size,
                              hipStream_t stream) {
    (void)in_sizes; (void)n_in; (void)out_size; (void)ws_size;
    const float* x  = (const float*)d_in[0];
    const float* Wq = (const float*)d_in[1];
    const float* Wk = (const float*)d_in[2];
    const float* Wv = (const float*)d_in[3];
    float* out = (float*)d_out;

    bf16* xb  = (bf16*)d_ws;
    bf16* Wb  = xb + (size_t)M_*KDIM;
    bf16* Qb  = Wb + (size_t)3*KDIM*KDIM;
    bf16* Kb  = Qb + (size_t)M_*KDIM;
    bf16* Vtb = Kb + (size_t)M_*KDIM;

    const int n4x = M_*KDIM/4;
    const int n4w = KDIM*KDIM/4;
    cvt_f32_to_bf16<<<(n4x+255)/256, 256, 0, stream>>>(x,  xb, n4x);
    cvt_f32_to_bf16<<<(n4w+255)/256, 256, 0, stream>>>(Wq, Wb,               n4w);
    cvt_f32_to_bf16<<<(n4w+255)/256, 256, 0, stream>>>(Wk, Wb + (size_t)KDIM*KDIM,   n4w);
    cvt_f32_to_bf16<<<(n4w+255)/256, 256, 0, stream>>>(Wv, Wb + (size_t)2*KDIM*KDIM, n4w);

    proj_gemm256<<<dim3(768), 512, 0, stream>>>(xb, Wb, Qb, Kb, Vtb);
    flash_attn3<<<dim3(BH_*16), 256, 0, stream>>>(Qb, Kb, Vtb, out);
}

// Round 6
// 153.559 us; speedup vs baseline: 1.3198x; 1.0920x over previous
//
#include <hip/hip_runtime.h>
#include <hip/hip_bf16.h>
#include <math.h>

#define B_   4
#define T_   2048
#define KDIM 1024
#define H_   16
#define D_   64
#define BH_  (B_*H_)      // 64
#define M_   (B_*T_)      // 8192
#define NKT  (KDIM/64)    // 16 K-tiles

typedef __bf16 bf16;
typedef __bf16 bf16x8 __attribute__((ext_vector_type(8)));
typedef __bf16 bf16x4 __attribute__((ext_vector_type(4)));
typedef float  f32x4  __attribute__((ext_vector_type(4)));
typedef float  f32x16 __attribute__((ext_vector_type(16)));
typedef unsigned int u32;
typedef u32 u32x4 __attribute__((ext_vector_type(4)));

static __device__ __forceinline__ f32x4 mfma16(bf16x8 a, bf16x8 b, f32x4 c) {
    return __builtin_amdgcn_mfma_f32_16x16x32_bf16(a, b, c, 0, 0, 0);
}
static __device__ __forceinline__ f32x16 mfma32(bf16x8 a, bf16x8 b, f32x16 c) {
    return __builtin_amdgcn_mfma_f32_32x32x16_bf16(a, b, c, 0, 0, 0);
}
static __device__ __forceinline__ float exp2_fast(float x) {
    float r; asm("v_exp_f32 %0, %1" : "=v"(r) : "v"(x)); return r;
}

// ---------------- merged fp32 -> bf16 conversion (one launch) ----------------
// dst layout: [xb 2097152 f4][Wq 262144 f4][Wk 262144 f4][Wv 262144 f4]
__global__ void cvt_all(const float* __restrict__ x,  const float* __restrict__ Wq,
                        const float* __restrict__ Wk, const float* __restrict__ Wv,
                        bf16* __restrict__ dst) {
    int i = blockIdx.x * blockDim.x + threadIdx.x;            // 0 .. 2883583
    const int NX = M_*KDIM/4, NW = KDIM*KDIM/4;
    const float* src;
    int j;
    if (i < NX)                { src = x;  j = i; }
    else if (i < NX + NW)      { src = Wq; j = i - NX; }
    else if (i < NX + 2*NW)    { src = Wk; j = i - NX - NW; }
    else                       { src = Wv; j = i - NX - 2*NW; }
    float4 v = reinterpret_cast<const float4*>(src)[j];
    bf16x4 o;
    o.x = (bf16)v.x; o.y = (bf16)v.y; o.z = (bf16)v.z; o.w = (bf16)v.w;
    reinterpret_cast<bf16x4*>(dst)[i] = o;
}

// ---------------- fused QKV GEMM: C[8192][3072] = x · Wflat^T ----------------
// 256x128 tile, BK=64, 8 waves (4M x 2N). 3-buffer / 1-barrier-per-K-step pipeline:
// stage(t+2) issued at iter top into the free buffer; counted vmcnt(6) — never drains.
// L2-tiled XCD mapping + 3-bit XOR LDS swizzle (0 conflicts, verified R5).
__global__ __launch_bounds__(512) void proj_gemm256(
    const bf16* __restrict__ xb, const bf16* __restrict__ Wflat,
    bf16* __restrict__ Qb, bf16* __restrict__ Kb, bf16* __restrict__ Vtb)
{
    __shared__ __align__(16) char As[3*32768];   // 3 x 256x64 bf16
    __shared__ __align__(16) char Bs[3*16384];   // 3 x 128x64 bf16

    const int tid  = threadIdx.x;
    const int wid  = tid >> 6;
    const int lane = tid & 63;
    const int l15  = lane & 15, l4 = lane >> 4;
    const int wavem = wid >> 1, waven = wid & 1;

    // L2-tiled XCD mapping (768 = 8 XCDs x 96; 32 concurrent/XCD = 4m x 8n)
    const int orig = blockIdx.x;
    const int xcd  = orig & 7;
    const int idx  = orig >> 3;
    const int mblk = xcd * 4 + (idx & 3);
    const int nblk = idx >> 2;
    const int row0 = mblk * 256, col0 = nblk * 128;

    // staging sources, pre-swizzled: LDS[r][cb] = G[r][cb ^ ((r&7)<<4)]
    const bf16* asrc[4];
#pragma unroll
    for (int q = 0; q < 4; ++q) {
        int c   = q*512 + tid;
        int rr  = c >> 3;
        int cb  = (c & 7) * 16;
        int cbs = cb ^ ((rr & 7) << 4);
        asrc[q] = xb + (size_t)(row0 + rr)*KDIM + (cbs >> 1);
    }
    const bf16* bsrc[2];
#pragma unroll
    for (int q = 0; q < 2; ++q) {
        int c   = q*512 + tid;
        int rr  = c >> 3;
        int cb  = (c & 7) * 16;
        int cbs = cb ^ ((rr & 7) << 4);
        bsrc[q] = Wflat + (size_t)(col0 + rr)*KDIM + (cbs >> 1);
    }

    auto stage = [&](int kt, int buf) {
        const int k0 = kt * 64;
        char* Ab = As + buf*32768;
        char* Bb = Bs + buf*16384;
#pragma unroll
        for (int q = 0; q < 4; ++q) {
            char* la = Ab + (q*512 + wid*64)*16;    // wave-uniform base
            __builtin_amdgcn_global_load_lds(
                (const __attribute__((address_space(1))) void*)(asrc[q] + k0),
                (__attribute__((address_space(3))) void*)la, 16, 0, 0);
        }
#pragma unroll
        for (int q = 0; q < 2; ++q) {
            char* lb = Bb + (q*512 + wid*64)*16;
            __builtin_amdgcn_global_load_lds(
                (const __attribute__((address_space(1))) void*)(bsrc[q] + k0),
                (__attribute__((address_space(3))) void*)lb, 16, 0, 0);
        }
    };

    f32x4 acc[4][4] = {};

    const int sw    = (l15 & 7) << 4;
    const int arow  = (wavem*64 + l15) * 128;
    const int brow  = (waven*64 + l15) * 128;

    // prologue: tiles 0,1 in buffers 0,1; wait tile 0 (6 of 12 outstanding), sync
    stage(0, 0);
    stage(1, 1);
    asm volatile("s_waitcnt vmcnt(6)" ::: "memory");
    __builtin_amdgcn_sched_barrier(0);
    __builtin_amdgcn_s_barrier();

#pragma unroll
    for (int t = 0; t < NKT; ++t) {
        const int bt = t % 3;
        const int b2 = (t + 2) % 3;
        // free buffer b2: its reads (tile t-1) finished before the barrier we just passed
        if (t + 2 < NKT) stage(t + 2, b2);

        const char* Ap = As + bt*32768;
        const char* Bp = Bs + bt*16384;
        bf16x8 af[2][4], bfr[2][4];
#pragma unroll
        for (int kk = 0; kk < 2; ++kk) {
            const int cbk = (kk*64 + l4*16) ^ sw;
#pragma unroll
            for (int m = 0; m < 4; ++m)
                af[kk][m] = *reinterpret_cast<const bf16x8*>(Ap + arow + m*2048 + cbk);
#pragma unroll
            for (int n = 0; n < 4; ++n)
                bfr[kk][n] = *reinterpret_cast<const bf16x8*>(Bp + brow + n*2048 + cbk);
        }
        __builtin_amdgcn_s_setprio(1);
#pragma unroll
        for (int kk = 0; kk < 2; ++kk)
#pragma unroll
            for (int m = 0; m < 4; ++m)
#pragma unroll
                for (int n = 0; n < 4; ++n)
                    acc[m][n] = mfma16(af[kk][m], bfr[kk][n], acc[m][n]);
        __builtin_amdgcn_s_setprio(0);

        if (t < NKT - 1) {
            if (t + 2 < NKT) {
                asm volatile("s_waitcnt vmcnt(6)" ::: "memory");   // tile t+1 landed; t+2 in flight
            } else {
                asm volatile("s_waitcnt vmcnt(0)" ::: "memory");   // last tile landed
            }
            __builtin_amdgcn_sched_barrier(0);
            __builtin_amdgcn_s_barrier();
        }
    }

    // ---- epilogue: C/D layout col=l15, row=l4*4+r ----
#pragma unroll
    for (int m = 0; m < 4; ++m)
#pragma unroll
        for (int n = 0; n < 4; ++n)
#pragma unroll
            for (int r = 0; r < 4; ++r) {
                int gi = row0 + wavem*64 + m*16 + l4*4 + r;   // 0..8191
                int gj = col0 + waven*64 + n*16 + l15;        // 0..3071
                int wz  = gj >> 10;
                int gjw = gj & 1023;
                float v = acc[m][n][r];
                if (wz == 0) v *= 0.18033688011112042f;       // 0.125*log2(e) into Q
                bf16 o = (bf16)v;
                int bb = gi >> 11, tt = gi & (T_-1);
                int hh = gjw >> 6, dd = gjw & (D_-1);
                size_t bh = (size_t)bb*H_ + hh;
                if (wz == 0)      Qb [(bh*T_ + tt)*D_ + dd] = o;
                else if (wz == 1) Kb [(bh*T_ + tt)*D_ + dd] = o;
                else              Vtb[(bh*D_ + dd)*T_ + tt] = o;
            }
}

// ---------------- causal flash attention v3 (unchanged, proven) ----------------
__global__ __launch_bounds__(256) void flash_attn3(
    const bf16* __restrict__ Qb, const bf16* __restrict__ Kb,
    const bf16* __restrict__ Vtb, float* __restrict__ out)
{
    __shared__ __align__(16) char Ksm[8192];   // [kv=64][d=64] bf16, rows XOR-swizzled
    __shared__ __align__(16) char Vsm[8192];   // [d=64][kv=64] bf16, rows XOR-swizzled

    const int tid  = threadIdx.x;
    const int wid  = tid >> 6;
    const int lane = tid & 63;
    const int l31  = lane & 31;
    const int hi   = lane >> 5;

    const int orig = blockIdx.x;                       // 1024 blocks
    const int wg   = (orig & 7) * 128 + (orig >> 3);
    const int bh   = wg >> 4;
    const int qblk = (15 - (wg & 15)) * 128;           // heavy tiles first per bh
    const int q0   = qblk + wid * 32;
    const int q_abs = q0 + l31;

    const bf16* qp = Qb + ((size_t)bh*T_ + q_abs)*D_ + hi*8;
    bf16x8 qf[4];
#pragma unroll
    for (int j = 0; j < 4; ++j)
        qf[j] = *reinterpret_cast<const bf16x8*>(qp + j*16);

    const bf16* kbase = Kb  + (size_t)bh*T_*D_;
    const bf16* vbase = Vtb + (size_t)bh*D_*T_;

    f32x16 o0 = {}; f32x16 o1 = {};
    float lsum = 0.f;

    const int my_nt  = (q0 + 31) >> 6;
    const int blk_nt = qblk/64 + 1;
    const int tmaskb = q_abs - 4*hi;

    const int r0 = tid >> 3,          r1 = (tid + 256) >> 3;
    const int e0 = (tid & 7) * 8,     e1 = e0;
    const u32 lds0 = (u32)((r0*128 + e0*2) ^ ((r0 & 7) << 4));
    const u32 lds1 = (u32)((r1*128 + e1*2) ^ ((r1 & 7) << 4));

    u32x4 kr0, kr1, vr0, vr1;
    auto issue = [&](int nt) {
        kr0 = *reinterpret_cast<const u32x4*>(kbase + ((size_t)(nt*64 + r0))*D_ + e0);
        kr1 = *reinterpret_cast<const u32x4*>(kbase + ((size_t)(nt*64 + r1))*D_ + e1);
        vr0 = *reinterpret_cast<const u32x4*>(vbase + (size_t)r0*T_ + nt*64 + e0);
        vr1 = *reinterpret_cast<const u32x4*>(vbase + (size_t)r1*T_ + nt*64 + e1);
    };
    issue(0);

    auto subtile = [&](int s, int kvb_abs, bool maskit, bf16x8& pA, bf16x8& pB) {
        f32x16 sacc = {};
        const int row = s*32 + l31;
        const int swk = (row & 7) << 4;
#pragma unroll
        for (int j = 0; j < 4; ++j) {
            bf16x8 kf = *reinterpret_cast<const bf16x8*>(Ksm + ((row*128 + j*32 + hi*16) ^ swk));
            sacc = mfma32(kf, qf[j], sacc);
        }
        const int tlim = tmaskb - kvb_abs;
        float p[16];
#pragma unroll
        for (int r = 0; r < 16; ++r) {
            const int crow0 = (r & 3) + 8*(r >> 2);
            float sv = sacc[r];
            if (maskit) sv = (crow0 > tlim) ? -INFINITY : sv;
            p[r] = exp2_fast(sv);
        }
        {
            float a0 = p[0]+p[1],   a1 = p[2]+p[3],   a2 = p[4]+p[5],   a3 = p[6]+p[7];
            float a4 = p[8]+p[9],   a5 = p[10]+p[11], a6 = p[12]+p[13], a7 = p[14]+p[15];
            lsum += ((a0+a1) + (a2+a3)) + ((a4+a5) + (a6+a7));
        }
        u32 w[8];
#pragma unroll
        for (int i = 0; i < 8; ++i) {
            u32 wv;
            asm("v_cvt_pk_bf16_f32 %0, %1, %2" : "=v"(wv) : "v"(p[2*i]), "v"(p[2*i+1]));
            w[i] = wv;
        }
        u32 a0w = w[0], a2w = w[2];
        asm("v_permlane32_swap_b32 %0, %1" : "+v"(a0w), "+v"(a2w));
        u32 a1w = w[1], a3w = w[3];
        asm("v_permlane32_swap_b32 %0, %1" : "+v"(a1w), "+v"(a3w));
        u32 b0w = w[4], b2w = w[6];
        asm("v_permlane32_swap_b32 %0, %1" : "+v"(b0w), "+v"(b2w));
        u32 b1w = w[5], b3w = w[7];
        asm("v_permlane32_swap_b32 %0, %1" : "+v"(b1w), "+v"(b3w));
        u32x4 A0 = {a0w, a1w, a2w, a3w};
        u32x4 A1 = {b0w, b1w, b2w, b3w};
        pA = __builtin_bit_cast(bf16x8, A0);
        pB = __builtin_bit_cast(bf16x8, A1);
    };

    auto pv = [&](int ks, bf16x8 pf) {
        const int swv = (l31 & 7) << 4;
        const int colb = ks*32 + hi*16;
        bf16x8 v0 = *reinterpret_cast<const bf16x8*>(Vsm + ((l31*128 + colb) ^ swv));
        bf16x8 v1 = *reinterpret_cast<const bf16x8*>(Vsm + (((32 + l31)*128 + colb) ^ swv));
        o0 = mfma32(v0, pf, o0);
        o1 = mfma32(v1, pf, o1);
    };

    for (int nt = 0; nt <= blk_nt; ++nt) {
        __syncthreads();
        *reinterpret_cast<u32x4*>(Ksm + lds0) = kr0;
        *reinterpret_cast<u32x4*>(Ksm + lds1) = kr1;
        *reinterpret_cast<u32x4*>(Vsm + lds0) = vr0;
        *reinterpret_cast<u32x4*>(Vsm + lds1) = vr1;
        __syncthreads();
        if (nt < blk_nt) issue(nt + 1);

        if (nt <= my_nt) {
            const bool partial = (nt == my_nt);
            const int  nsub = (!partial || (q0 & 32)) ? 2 : 1;
            bf16x8 pA, pB;
            subtile(0, nt*64, partial, pA, pB);
            pv(0, pA);
            pv(1, pB);
            if (nsub == 2) {
                subtile(1, nt*64 + 32, partial, pA, pB);
                pv(2, pA);
                pv(3, pB);
            }
        }
    }

    lsum += __shfl_xor(lsum, 32);
    const float inv = 1.0f / lsum;
    const int bb = bh >> 4, hh = bh & 15;
    float* orow = out + ((size_t)bb*T_ + q_abs)*KDIM + hh*64 + hi*4;
#pragma unroll
    for (int g = 0; g < 4; ++g) {
        f32x4 v0, v1;
#pragma unroll
        for (int j = 0; j < 4; ++j) { v0[j] = o0[g*4+j]*inv; v1[j] = o1[g*4+j]*inv; }
        *reinterpret_cast<f32x4*>(orow + g*8)      = v0;
        *reinterpret_cast<f32x4*>(orow + 32 + g*8) = v1;
    }
}

extern "C" void kernel_launch(void* const* d_in, const int* in_sizes, int n_in,
                              void* d_out, int out_size, void* d_ws, size_t ws_size,
                              hipStream_t stream) {
    (void)in_sizes; (void)n_in; (void)out_size; (void)ws_size;
    const float* x  = (const float*)d_in[0];
    const float* Wq = (const float*)d_in[1];
    const float* Wk = (const float*)d_in[2];
    const float* Wv = (const float*)d_in[3];
    float* out = (float*)d_out;

    bf16* xb  = (bf16*)d_ws;
    bf16* Wb  = xb + (size_t)M_*KDIM;
    bf16* Qb  = Wb + (size_t)3*KDIM*KDIM;
    bf16* Kb  = Qb + (size_t)M_*KDIM;
    bf16* Vtb = Kb + (size_t)M_*KDIM;

    const int n4 = (M_*KDIM + 3*KDIM*KDIM) / 4;          // 2883584
    cvt_all<<<(n4 + 255)/256, 256, 0, stream>>>(x, Wq, Wk, Wv, xb);

    proj_gemm256<<<dim3(768), 512, 0, stream>>>(xb, Wb, Qb, Kb, Vtb);
    flash_attn3<<<dim3(BH_*16), 256, 0, stream>>>(Qb, Kb, Vtb, out);
}